// Round 2
// baseline (1139.139 us; speedup 1.0000x reference)
//
#include <hip/hip_runtime.h>
#include <hip/hip_bf16.h>

// CrossAttention: B=4, H=W=64 (N=4096), C=512, FG=64.
// Pipeline: cast/transpose -> f,g proj (fp32, split to bf16 hi/lo)
//           -> h proj (bf16 MFMA, transposed bf16 out)
//           -> S1 stats (m,l partials, 8192 blocks) -> S2 merge
//           -> S3 attention (single pass, beta direct, PV) -> o proj.

#define BATCH 4
#define NSEQ  4096
#define CHN   512
#define FGW   64
#define MROWS (BATCH * NSEQ)  // 16384
#define KCH   8               // key chunks in stats kernel
#define KCHLEN (NSEQ / KCH)   // 512

using f32x4  = __attribute__((ext_vector_type(4))) float;
using bf16x8 = __attribute__((ext_vector_type(8))) short;
using u32x4  = __attribute__((ext_vector_type(4))) unsigned int;

__device__ __forceinline__ unsigned short f2bf(float f) {
  union { __hip_bfloat16 h; unsigned short u; } v;
  v.h = __float2bfloat16(f);
  return v.u;
}
__device__ __forceinline__ float bf2f(unsigned short u) {
  return __uint_as_float(((unsigned int)u) << 16);
}
// XOR swizzle for [R][64]-ushort LDS tiles (guide G4 / T2).
__device__ __forceinline__ int swz(int r, int c) {
  return r * 64 + (c ^ ((r & 7) << 3));
}
__device__ __forceinline__ bf16x8 ld8(const unsigned short* base, int r, int c) {
  return *reinterpret_cast<const bf16x8*>(base + swz(r, c));
}

// ---------------- K0a: f32 -> bf16 elementwise (for l) ----------------
__global__ __launch_bounds__(256) void cast_bf16_kernel(
    const float* __restrict__ in, unsigned short* __restrict__ out) {
  int i = (blockIdx.x * 256 + threadIdx.x) * 4;
  float4 v = *reinterpret_cast<const float4*>(in + i);
  ushort4 o;
  o.x = f2bf(v.x); o.y = f2bf(v.y); o.z = f2bf(v.z); o.w = f2bf(v.w);
  *reinterpret_cast<ushort4*>(out + i) = o;
}

// ---------------- K0b: W[512][512] -> Wt[n][k] bf16 ----------------
__global__ __launch_bounds__(256) void transpose_w_kernel(
    const float* __restrict__ w, unsigned short* __restrict__ wt) {
  int t = blockIdx.x * 256 + threadIdx.x;  // 262144
  int k = t >> 9, n = t & 511;
  wt[n * 512 + k] = f2bf(w[t]);
}

// ------------- K1: f/g projection, fp32 accuracy, split hi/lo bf16 -------------
__global__ __launch_bounds__(256) void fg_proj_kernel(
    const float* __restrict__ x, const float* __restrict__ w,
    const float* __restrict__ bias,
    unsigned short* __restrict__ out_hi, unsigned short* __restrict__ out_lo) {
  __shared__ float xs[16][512];
  const int t = threadIdx.x;
  const int row0 = blockIdx.x * 16;
  {
    const float4* src = reinterpret_cast<const float4*>(x + (size_t)row0 * 512);
    float4* dst = reinterpret_cast<float4*>(&xs[0][0]);
#pragma unroll
    for (int i = 0; i < 8; i++) dst[t + i * 256] = src[t + i * 256];
  }
  __syncthreads();
  const int col = t & 63;
  const int rb = (t >> 6) * 4;
  float a0 = 0.f, a1 = 0.f, a2 = 0.f, a3 = 0.f;
#pragma unroll 8
  for (int k = 0; k < 512; k++) {
    float wv = w[k * 64 + col];
    a0 = fmaf(xs[rb + 0][k], wv, a0);
    a1 = fmaf(xs[rb + 1][k], wv, a1);
    a2 = fmaf(xs[rb + 2][k], wv, a2);
    a3 = fmaf(xs[rb + 3][k], wv, a3);
  }
  const float bv = bias[col];
  float av[4] = {a0, a1, a2, a3};
#pragma unroll
  for (int j = 0; j < 4; j++) {
    float v = fmaxf(av[j] + bv, 0.f);
    unsigned short hi = f2bf(v);
    unsigned short lo = f2bf(v - bf2f(hi));
    size_t idx = (size_t)(row0 + rb + j) * FGW + col;
    out_hi[idx] = hi;
    out_lo[idx] = lo;
  }
}

// ------------- K2/K4: M=16384,N=512,K=512 bf16 MFMA GEMM + bias + relu -------------
template <int MODE>
__global__ __launch_bounds__(256) void gemm512_kernel(
    const unsigned short* __restrict__ A,
    const unsigned short* __restrict__ Bt,
    const float* __restrict__ bias,
    void* __restrict__ outp) {
  __shared__ unsigned short As[128 * 64], Bs[128 * 64];
  const int t = threadIdx.x;
  const int lane = t & 63;
  const int wid = t >> 6;
  const int wr = wid >> 1, wc = wid & 1;
  const int m0 = blockIdx.y * 128;
  const int n0 = blockIdx.x * 128;

  f32x4 acc[4][4] = {};
  const int srow = t >> 1;
  const int spart = (t & 1) * 32;
#pragma unroll 1
  for (int kt = 0; kt < 8; kt++) {
    const int k0 = kt * 64;
    __syncthreads();
    {
      const unsigned short* ga = A + (size_t)(m0 + srow) * 512 + k0 + spart;
      const unsigned short* gb = Bt + (size_t)(n0 + srow) * 512 + k0 + spart;
#pragma unroll
      for (int i = 0; i < 4; i++) {
        u32x4 va = *reinterpret_cast<const u32x4*>(ga + i * 8);
        u32x4 vb = *reinterpret_cast<const u32x4*>(gb + i * 8);
        *reinterpret_cast<u32x4*>(As + swz(srow, spart + i * 8)) = va;
        *reinterpret_cast<u32x4*>(Bs + swz(srow, spart + i * 8)) = vb;
      }
    }
    __syncthreads();
#pragma unroll
    for (int ks = 0; ks < 2; ks++) {
      const int koff = ks * 32 + (lane >> 4) * 8;
      bf16x8 a[4], bb[4];
#pragma unroll
      for (int rt = 0; rt < 4; rt++) a[rt] = ld8(As, wr * 64 + rt * 16 + (lane & 15), koff);
#pragma unroll
      for (int ct = 0; ct < 4; ct++) bb[ct] = ld8(Bs, wc * 64 + ct * 16 + (lane & 15), koff);
#pragma unroll
      for (int rt = 0; rt < 4; rt++)
#pragma unroll
        for (int ct = 0; ct < 4; ct++)
          acc[rt][ct] = __builtin_amdgcn_mfma_f32_16x16x32_bf16(a[rt], bb[ct], acc[rt][ct], 0, 0, 0);
    }
  }
#pragma unroll
  for (int rt = 0; rt < 4; rt++)
#pragma unroll
    for (int ct = 0; ct < 4; ct++) {
      const int n = n0 + wc * 64 + ct * 16 + (lane & 15);
      const float bv = bias[n];
      const int rowb = m0 + wr * 64 + rt * 16 + (lane >> 4) * 4;
      if (MODE == 0) {
        unsigned short* ht = (unsigned short*)outp;
        const int bb2 = rowb >> 12, key = rowb & 4095;
        ushort4 v;
        v.x = f2bf(fmaxf(acc[rt][ct][0] + bv, 0.f));
        v.y = f2bf(fmaxf(acc[rt][ct][1] + bv, 0.f));
        v.z = f2bf(fmaxf(acc[rt][ct][2] + bv, 0.f));
        v.w = f2bf(fmaxf(acc[rt][ct][3] + bv, 0.f));
        *reinterpret_cast<ushort4*>(ht + ((size_t)bb2 * CHN + n) * NSEQ + key) = v;
      } else {
        float* oo = (float*)outp;
#pragma unroll
        for (int rr = 0; rr < 4; rr++)
          oo[(size_t)(rowb + rr) * CHN + n] = fmaxf(acc[rt][ct][rr] + bv, 0.f);
      }
    }
}

// ------------- S1: softmax stats partials, key-chunked, no LDS staging -------------
// grid = BATCH * 256 * KCH = 8192 blocks, 4 waves. Wave w covers key cols
// [16w,16w+16) of each 64-key step; 8 steps over its 512-key chunk.
__global__ __launch_bounds__(256) void stats_kernel(
    const unsigned short* __restrict__ g_hi, const unsigned short* __restrict__ g_lo,
    const unsigned short* __restrict__ f_hi, const unsigned short* __restrict__ f_lo,
    float2* __restrict__ mpart) {  // [MROWS][KCH]
  __shared__ float msc[4][16], lsc[4][16];
  const int t = threadIdx.x, lane = t & 63, w = t >> 6;
  const int bid = blockIdx.x;
  const int kc = bid & 7;
  const int qt = (bid >> 3) & 255;
  const int b = bid >> 11;
  const size_t grow = (size_t)b * NSEQ + qt * 16;
  const int koff = (lane >> 4) * 8;

  bf16x8 agh[2], agl[2];
  {
    const unsigned short* gh = g_hi + (grow + (lane & 15)) * FGW;
    const unsigned short* gl = g_lo + (grow + (lane & 15)) * FGW;
#pragma unroll
    for (int ks = 0; ks < 2; ks++) {
      agh[ks] = *reinterpret_cast<const bf16x8*>(gh + ks * 32 + koff);
      agl[ks] = *reinterpret_cast<const bf16x8*>(gl + ks * 32 + koff);
    }
  }
  float m_run[4], l_run[4];
#pragma unroll
  for (int r = 0; r < 4; r++) { m_run[r] = -INFINITY; l_run[r] = 0.f; }

  const size_t frow = (size_t)b * NSEQ + kc * KCHLEN + w * 16 + (lane & 15);
#pragma unroll 1
  for (int kb = 0; kb < KCHLEN / 64; kb++) {
    const unsigned short* fh = f_hi + (frow + kb * 64) * FGW;
    const unsigned short* fl = f_lo + (frow + kb * 64) * FGW;
    f32x4 sacc = {};
#pragma unroll
    for (int ks = 0; ks < 2; ks++) {
      bf16x8 bh = *reinterpret_cast<const bf16x8*>(fh + ks * 32 + koff);
      bf16x8 bl = *reinterpret_cast<const bf16x8*>(fl + ks * 32 + koff);
      sacc = __builtin_amdgcn_mfma_f32_16x16x32_bf16(agh[ks], bh, sacc, 0, 0, 0);
      sacc = __builtin_amdgcn_mfma_f32_16x16x32_bf16(agh[ks], bl, sacc, 0, 0, 0);
      sacc = __builtin_amdgcn_mfma_f32_16x16x32_bf16(agl[ks], bh, sacc, 0, 0, 0);
    }
#pragma unroll
    for (int r = 0; r < 4; r++) {
      float s = sacc[r];
      float mx = s;
      mx = fmaxf(mx, __shfl_xor(mx, 1));
      mx = fmaxf(mx, __shfl_xor(mx, 2));
      mx = fmaxf(mx, __shfl_xor(mx, 4));
      mx = fmaxf(mx, __shfl_xor(mx, 8));
      float mn = fmaxf(m_run[r], mx);
      float e = __expf(s - mn);
      e += __shfl_xor(e, 1);
      e += __shfl_xor(e, 2);
      e += __shfl_xor(e, 4);
      e += __shfl_xor(e, 8);
      l_run[r] = l_run[r] * __expf(m_run[r] - mn) + e;
      m_run[r] = mn;
    }
  }
  if ((lane & 15) == 0) {
#pragma unroll
    for (int r = 0; r < 4; r++) {
      int row = (lane >> 4) * 4 + r;
      msc[w][row] = m_run[r];
      lsc[w][row] = l_run[r];
    }
  }
  __syncthreads();
  if (w == 0 && lane < 16) {
    float m = msc[0][lane];
    for (int w2 = 1; w2 < 4; w2++) m = fmaxf(m, msc[w2][lane]);
    float l = 0.f;
    for (int w2 = 0; w2 < 4; w2++) l += lsc[w2][lane] * __expf(msc[w2][lane] - m);
    mpart[(grow + lane) * KCH + kc] = make_float2(m, l);
  }
}

// ------------- S2: merge stats partials -> m_fin, 1/l_fin -------------
__global__ __launch_bounds__(256) void stats_merge_kernel(
    const float2* __restrict__ mpart, float* __restrict__ m_fin,
    float* __restrict__ li_fin) {
  int row = blockIdx.x * 256 + threadIdx.x;
  float2 v[KCH];
#pragma unroll
  for (int i = 0; i < KCH; i++) v[i] = mpart[(size_t)row * KCH + i];
  float m = v[0].x;
#pragma unroll
  for (int i = 1; i < KCH; i++) m = fmaxf(m, v[i].x);
  float l = 0.f;
#pragma unroll
  for (int i = 0; i < KCH; i++) l += v[i].y * __expf(v[i].x - m);
  m_fin[row] = m;
  li_fin[row] = 1.f / l;
}

// ------------- S3: single-pass attention: s -> beta (direct) -> PV -------------
// grid = 1024 blocks (QBLK=16 rows each), 4 waves. Wave w: s cols [16w,16w+16),
// PV cols [128w,128w+128). One barrier per 64-key step.
__global__ __launch_bounds__(256, 3) void attn2_kernel(
    const unsigned short* __restrict__ g_hi, const unsigned short* __restrict__ g_lo,
    const unsigned short* __restrict__ f_hi, const unsigned short* __restrict__ f_lo,
    const unsigned short* __restrict__ h_t,
    const float* __restrict__ m_fin, const float* __restrict__ li_fin,
    float* __restrict__ beta_out, unsigned short* __restrict__ o_att) {
  __shared__ unsigned short p_bf[2][16 * 64];
  const int t = threadIdx.x, lane = t & 63, w = t >> 6;
  // bijective XCD swizzle: each XCD handles exactly one batch (h_t slice = 4MB = L2)
  const int bid = blockIdx.x;
  const int xcd = bid & 7, j = bid >> 3;
  const int b = xcd & 3;
  const int qt = (xcd >> 2) * 128 + j;
  const size_t grow = (size_t)b * NSEQ + qt * 16;
  const int koff = (lane >> 4) * 8;
  const int rbase = (lane >> 4) * 4;

  bf16x8 agh[2], agl[2];
  {
    const unsigned short* gh = g_hi + (grow + (lane & 15)) * FGW;
    const unsigned short* gl = g_lo + (grow + (lane & 15)) * FGW;
#pragma unroll
    for (int ks = 0; ks < 2; ks++) {
      agh[ks] = *reinterpret_cast<const bf16x8*>(gh + ks * 32 + koff);
      agl[ks] = *reinterpret_cast<const bf16x8*>(gl + ks * 32 + koff);
    }
  }
  float m_r[4], li_r[4];
#pragma unroll
  for (int r = 0; r < 4; r++) {
    m_r[r] = m_fin[grow + rbase + r];
    li_r[r] = li_fin[grow + rbase + r];
  }

  const unsigned short* fb_h = f_hi + ((size_t)b * NSEQ + w * 16 + (lane & 15)) * FGW;
  const unsigned short* fb_l = f_lo + ((size_t)b * NSEQ + w * 16 + (lane & 15)) * FGW;
  bf16x8 fh[2], fl[2];
#pragma unroll
  for (int ks = 0; ks < 2; ks++) {
    fh[ks] = *reinterpret_cast<const bf16x8*>(fb_h + ks * 32 + koff);
    fl[ks] = *reinterpret_cast<const bf16x8*>(fb_l + ks * 32 + koff);
  }

  const unsigned short* hb = h_t + ((size_t)b * CHN + w * 128 + (lane & 15)) * NSEQ;
  f32x4 oacc[8] = {};

#pragma unroll 1
  for (int kb = 0; kb < 64; kb++) {
    f32x4 sacc = {};
#pragma unroll
    for (int ks = 0; ks < 2; ks++) {
      sacc = __builtin_amdgcn_mfma_f32_16x16x32_bf16(agh[ks], fh[ks], sacc, 0, 0, 0);
      sacc = __builtin_amdgcn_mfma_f32_16x16x32_bf16(agh[ks], fl[ks], sacc, 0, 0, 0);
      sacc = __builtin_amdgcn_mfma_f32_16x16x32_bf16(agl[ks], fh[ks], sacc, 0, 0, 0);
    }
    const int buf = kb & 1;
#pragma unroll
    for (int r = 0; r < 4; r++) {
      float bta = __expf(sacc[r] - m_r[r]) * li_r[r];
      beta_out[(grow + rbase + r) * (size_t)NSEQ + kb * 64 + w * 16 + (lane & 15)] = bta;
      p_bf[buf][swz(rbase + r, w * 16 + (lane & 15))] = f2bf(bta);
    }
    __syncthreads();
    // prefetch next f fragments: a full PV phase to cover their latency
    if (kb < 63) {
      const unsigned short* nh = fb_h + (size_t)(kb + 1) * 64 * FGW;
      const unsigned short* nl = fb_l + (size_t)(kb + 1) * 64 * FGW;
#pragma unroll
      for (int ks = 0; ks < 2; ks++) {
        fh[ks] = *reinterpret_cast<const bf16x8*>(nh + ks * 32 + koff);
        fl[ks] = *reinterpret_cast<const bf16x8*>(nl + ks * 32 + koff);
      }
    }
    const unsigned short* hkb = hb + kb * 64 + koff;
#pragma unroll
    for (int ks = 0; ks < 2; ks++) {
      bf16x8 ap = ld8(p_bf[buf], lane & 15, ks * 32 + koff);
#pragma unroll
      for (int ct = 0; ct < 8; ct++) {
        bf16x8 hv = *reinterpret_cast<const bf16x8*>(hkb + (size_t)ct * 16 * NSEQ + ks * 32);
        oacc[ct] = __builtin_amdgcn_mfma_f32_16x16x32_bf16(ap, hv, oacc[ct], 0, 0, 0);
      }
    }
  }
#pragma unroll
  for (int ct = 0; ct < 8; ct++) {
    int col = w * 128 + ct * 16 + (lane & 15);
#pragma unroll
    for (int r = 0; r < 4; r++)
      o_att[(grow + rbase + r) * CHN + col] = f2bf(oacc[ct][r]);
  }
}

extern "C" void kernel_launch(void* const* d_in, const int* in_sizes, int n_in,
                              void* d_out, int out_size, void* d_ws, size_t ws_size,
                              hipStream_t stream) {
  (void)in_sizes; (void)n_in; (void)out_size; (void)ws_size;
  const float* l   = (const float*)d_in[0];
  const float* r   = (const float*)d_in[1];
  const float* wf  = (const float*)d_in[2];
  const float* wg  = (const float*)d_in[3];
  const float* wh  = (const float*)d_in[4];
  const float* wo  = (const float*)d_in[5];
  const float* bf_ = (const float*)d_in[6];
  const float* bg  = (const float*)d_in[7];
  const float* bh  = (const float*)d_in[8];
  const float* bo  = (const float*)d_in[9];

  char* ws = (char*)d_ws;  // ~60 MB used
  unsigned short* f_hi  = (unsigned short*)(ws + (0ull  << 20));
  unsigned short* f_lo  = (unsigned short*)(ws + (2ull  << 20));
  unsigned short* g_hi  = (unsigned short*)(ws + (4ull  << 20));
  unsigned short* g_lo  = (unsigned short*)(ws + (6ull  << 20));
  unsigned short* l_bf  = (unsigned short*)(ws + (8ull  << 20));  // 16 MB
  unsigned short* wh_t  = (unsigned short*)(ws + (24ull << 20));
  unsigned short* wo_t  = (unsigned short*)(ws + (25ull << 20));
  unsigned short* h_t   = (unsigned short*)(ws + (26ull << 20));  // 16 MB
  unsigned short* o_att = (unsigned short*)(ws + (42ull << 20));  // 16 MB
  float2*         mpart = (float2*)(ws + (58ull << 20));          // 1 MB
  float*          m_fin = (float*)(ws + (59ull << 20));           // 64 KB
  float*          li_fin= (float*)(ws + (59ull << 20) + (1ull << 19));

  float* out_o = (float*)d_out;
  float* out_beta = out_o + (size_t)MROWS * CHN;

  cast_bf16_kernel<<<MROWS * CHN / 1024, 256, 0, stream>>>(l, l_bf);
  transpose_w_kernel<<<512 * 512 / 256, 256, 0, stream>>>(wh, wh_t);
  transpose_w_kernel<<<512 * 512 / 256, 256, 0, stream>>>(wo, wo_t);
  fg_proj_kernel<<<MROWS / 16, 256, 0, stream>>>(l, wf, bf_, f_hi, f_lo);
  fg_proj_kernel<<<MROWS / 16, 256, 0, stream>>>(r, wg, bg, g_hi, g_lo);
  gemm512_kernel<0><<<dim3(4, 128), 256, 0, stream>>>(l_bf, wh_t, bh, (void*)h_t);
  stats_kernel<<<BATCH * 256 * KCH, 256, 0, stream>>>(g_hi, g_lo, f_hi, f_lo, mpart);
  stats_merge_kernel<<<MROWS / 256, 256, 0, stream>>>(mpart, m_fin, li_fin);
  attn2_kernel<<<1024, 256, 0, stream>>>(g_hi, g_lo, f_hi, f_lo, h_t, m_fin, li_fin,
                                         out_beta, o_att);
  gemm512_kernel<1><<<dim3(4, 128), 256, 0, stream>>>(o_att, wo_t, bo, (void*)out_o);
}